// Round 1
// baseline (639.435 us; speedup 1.0000x reference)
//
#include <hip/hip_runtime.h>
#include <math.h>

#define D  32
#define BN 16384
#define PP 16

__device__ __forceinline__ float sigf(float x) { return 1.0f / (1.0f + __expf(-x)); }
__device__ __forceinline__ float tanh_fast(float x) {
    float e = __expf(2.0f * x);
    return 1.0f - 2.0f / (e + 1.0f);
}
__device__ __forceinline__ float logsigf(float x) {
    float ax = fabsf(x);
    float l = log1pf(__expf(-ax));
    return (x >= 0.0f) ? -l : x - l;
}

// One block = 64 pairs (4 consecutive b's x 16 p's). 4 waves; wave w owns hidden
// units [8w, 8w+8). lane (tid&63) = local pair. Weight addresses are wave-uniform
// (readfirstlane) -> scalar loads, SGPR operand in v_fmac.
template<int L, int T>
__global__ __launch_bounds__(256, 3)
void hop_kernel(const float* __restrict__ user_table,
                const float* __restrict__ ent_table,
                const float* __restrict__ rel_table,
                const float* __restrict__ w_ih,   // (128,64)
                const float* __restrict__ w_hh,   // (128,32)
                const float* __restrict__ b_ih,   // (128)
                const float* __restrict__ b_hh,   // (128)
                const int*   __restrict__ users,
                const int*   __restrict__ items,
                const int*   __restrict__ lp,     // (NE,P,L)
                float* __restrict__ final_out)    // (B,32)
{
    __shared__ float h_sh[64][33];
    __shared__ float c_sh[64][33];

    const int tid   = threadIdx.x;
    const int lane  = tid & 63;
    const int wave8 = __builtin_amdgcn_readfirstlane((tid >> 6) * 8);

    const int pairIdx = blockIdx.x * 64 + lane;
    const int b = pairIdx >> 4;
    const int p = pairIdx & 15;
    const int item = items[b];
    const int user = users[b];
    const int* __restrict__ il = lp + ((size_t)item * PP + p) * L;

    float x[64];
    float hprev[32];

    // ---------------- step 0: x = [u, seed], h=c=0 (f-gate irrelevant) --------
    {
        const int seed = il[0];
        const float4* s0 = reinterpret_cast<const float4*>(user_table + (size_t)user * D);
        const float4* s1 = reinterpret_cast<const float4*>(ent_table + (size_t)seed * D);
        #pragma unroll
        for (int q = 0; q < 8; ++q) {
            float4 v = s0[q];
            x[4*q+0] = v.x; x[4*q+1] = v.y; x[4*q+2] = v.z; x[4*q+3] = v.w;
        }
        #pragma unroll
        for (int q = 0; q < 8; ++q) {
            float4 v = s1[q];
            x[32+4*q+0] = v.x; x[32+4*q+1] = v.y; x[32+4*q+2] = v.z; x[32+4*q+3] = v.w;
        }
    }
    #pragma unroll 1
    for (int u = 0; u < 8; ++u) {
        const int j = wave8 + u;
        const float* __restrict__ wi0 = w_ih + (size_t)(j     ) * 64;
        const float* __restrict__ wi2 = w_ih + (size_t)(j + 64) * 64;
        const float* __restrict__ wi3 = w_ih + (size_t)(j + 96) * 64;
        float gi = b_ih[j     ] + b_hh[j     ];
        float gg = b_ih[j + 64] + b_hh[j + 64];
        float go = b_ih[j + 96] + b_hh[j + 96];
        #pragma unroll
        for (int k = 0; k < 64; ++k) {
            float xv = x[k];
            gi = fmaf(wi0[k], xv, gi);
            gg = fmaf(wi2[k], xv, gg);
            go = fmaf(wi3[k], xv, go);
        }
        float cc = sigf(gi) * tanh_fast(gg);
        c_sh[lane][j] = cc;
        h_sh[lane][j] = sigf(go) * tanh_fast(cc);
    }

    // ---------------- steps 1..T-1: x = [rel, tail] --------------------------
    #pragma unroll 1
    for (int t = 1; t < T; ++t) {
        __syncthreads();                    // h writes of prev step done
        #pragma unroll
        for (int k = 0; k < 32; ++k) hprev[k] = h_sh[lane][k];
        __syncthreads();                    // everyone copied before overwrite

        const int ridx = il[2*t - 1];
        const int tidx = il[2*t];
        const float4* s0 = reinterpret_cast<const float4*>(rel_table + (size_t)ridx * D);
        const float4* s1 = reinterpret_cast<const float4*>(ent_table + (size_t)tidx * D);
        #pragma unroll
        for (int q = 0; q < 8; ++q) {
            float4 v = s0[q];
            x[4*q+0] = v.x; x[4*q+1] = v.y; x[4*q+2] = v.z; x[4*q+3] = v.w;
        }
        #pragma unroll
        for (int q = 0; q < 8; ++q) {
            float4 v = s1[q];
            x[32+4*q+0] = v.x; x[32+4*q+1] = v.y; x[32+4*q+2] = v.z; x[32+4*q+3] = v.w;
        }

        #pragma unroll 1
        for (int u = 0; u < 8; ++u) {
            const int j = wave8 + u;
            const float* __restrict__ wi0 = w_ih + (size_t)(j     ) * 64;
            const float* __restrict__ wi1 = w_ih + (size_t)(j + 32) * 64;
            const float* __restrict__ wi2 = w_ih + (size_t)(j + 64) * 64;
            const float* __restrict__ wi3 = w_ih + (size_t)(j + 96) * 64;
            float gi = b_ih[j     ] + b_hh[j     ];
            float gf = b_ih[j + 32] + b_hh[j + 32];
            float gg = b_ih[j + 64] + b_hh[j + 64];
            float go = b_ih[j + 96] + b_hh[j + 96];
            #pragma unroll
            for (int k = 0; k < 64; ++k) {
                float xv = x[k];
                gi = fmaf(wi0[k], xv, gi);
                gf = fmaf(wi1[k], xv, gf);
                gg = fmaf(wi2[k], xv, gg);
                go = fmaf(wi3[k], xv, go);
            }
            const float* __restrict__ wh0 = w_hh + (size_t)(j     ) * 32;
            const float* __restrict__ wh1 = w_hh + (size_t)(j + 32) * 32;
            const float* __restrict__ wh2 = w_hh + (size_t)(j + 64) * 32;
            const float* __restrict__ wh3 = w_hh + (size_t)(j + 96) * 32;
            #pragma unroll
            for (int k = 0; k < 32; ++k) {
                float hv = hprev[k];
                gi = fmaf(wh0[k], hv, gi);
                gf = fmaf(wh1[k], hv, gf);
                gg = fmaf(wh2[k], hv, gg);
                go = fmaf(wh3[k], hv, go);
            }
            float cold = c_sh[lane][j];
            float cc = sigf(gf) * cold + sigf(gi) * tanh_fast(gg);
            c_sh[lane][j] = cc;
            h_sh[lane][j] = sigf(go) * tanh_fast(cc);
        }
    }

    // ---------------- epilogue: sum over p (16-lane groups) ------------------
    #pragma unroll
    for (int u = 0; u < 8; ++u) {
        float v = h_sh[lane][wave8 + u];
        v += __shfl_xor(v, 1);
        v += __shfl_xor(v, 2);
        v += __shfl_xor(v, 4);
        v += __shfl_xor(v, 8);
        if ((lane & 15) == 0)
            final_out[(size_t)b * D + wave8 + u] = v;
    }
}

// out_emb[b][j] = agg_b[j] + sum_k (src[b][k] + final[b][k]) * agg_w[j][k]
__global__ __launch_bounds__(256)
void agg_kernel(const float* __restrict__ src_emb,   // may be null -> gather ent[items]
                const float* __restrict__ ent_table,
                const int*   __restrict__ items,
                const float* __restrict__ final_in,
                const float* __restrict__ agg_w,
                const float* __restrict__ agg_b,
                float* __restrict__ out_emb)
{
    const int t = blockIdx.x * 256 + threadIdx.x;   // B*32 threads
    const int b = t >> 5;
    const int j = t & 31;
    const float* __restrict__ src =
        src_emb ? (src_emb + (size_t)b * D) : (ent_table + (size_t)items[b] * D);
    const float* __restrict__ fin = final_in + (size_t)b * D;
    const float* __restrict__ w   = agg_w + (size_t)j * D;
    float acc = agg_b[j];
    #pragma unroll
    for (int k = 0; k < D; ++k) acc = fmaf(src[k] + fin[k], w[k], acc);
    out_emb[t] = acc;
}

__global__ __launch_bounds__(256)
void score_kernel(const float* __restrict__ user_table,
                  const float* __restrict__ emb,
                  const int*   __restrict__ users,
                  const int*   __restrict__ items,
                  const int*   __restrict__ ratings,
                  float* __restrict__ out,
                  float* __restrict__ partials)
{
    __shared__ float red[4];
    const int t = threadIdx.x;
    const int b = blockIdx.x * 256 + t;
    const float* __restrict__ u = user_table + (size_t)users[b] * D;
    const float* __restrict__ e = emb + (size_t)b * D;
    float s = 0.0f;
    #pragma unroll
    for (int k = 0; k < D; ++k) s = fmaf(u[k], e[k], s);
    out[1 + b]      = sigf(s);
    out[1 + BN + b] = (float)items[b];
    float r = (float)ratings[b];
    float term = r * logsigf(s) + (1.0f - r) * logsigf(-s);
    #pragma unroll
    for (int m = 1; m < 64; m <<= 1) term += __shfl_xor(term, m);
    if ((t & 63) == 0) red[t >> 6] = term;
    __syncthreads();
    if (t == 0) partials[blockIdx.x] = red[0] + red[1] + red[2] + red[3];
}

__global__ void loss_kernel(const float* __restrict__ partials, float* __restrict__ out)
{
    const int t = threadIdx.x;   // 64 threads
    float v = partials[t];
    #pragma unroll
    for (int m = 1; m < 64; m <<= 1) v += __shfl_xor(v, m);
    if (t == 0) out[0] = -v / (float)BN;
}

extern "C" void kernel_launch(void* const* d_in, const int* in_sizes, int n_in,
                              void* d_out, int out_size, void* d_ws, size_t ws_size,
                              hipStream_t stream)
{
    const float* user_table = (const float*)d_in[0];
    const float* ent_table  = (const float*)d_in[1];
    const float* rel_table  = (const float*)d_in[2];
    const float* w_ih0 = (const float*)d_in[3];
    const float* w_hh0 = (const float*)d_in[4];
    const float* b_ih0 = (const float*)d_in[5];
    const float* b_hh0 = (const float*)d_in[6];
    const float* w_ih1 = (const float*)d_in[7];
    const float* w_hh1 = (const float*)d_in[8];
    const float* b_ih1 = (const float*)d_in[9];
    const float* b_hh1 = (const float*)d_in[10];
    const float* agg_w = (const float*)d_in[11];
    const float* agg_b = (const float*)d_in[12];
    const int* users   = (const int*)d_in[13];
    const int* items   = (const int*)d_in[14];
    const int* ratings = (const int*)d_in[15];
    const int* lp0     = (const int*)d_in[16];
    const int* lp1     = (const int*)d_in[17];
    float* out = (float*)d_out;

    float* ws        = (float*)d_ws;
    float* final_buf = ws;                          // B*32
    float* emb0      = ws + (size_t)BN * D;         // B*32
    float* emb1      = ws + 2 * (size_t)BN * D;     // B*32
    float* partials  = ws + 3 * (size_t)BN * D;     // 64

    const int hop_blocks = (BN * PP) / 64;          // 4096
    hop_kernel<3, 2><<<hop_blocks, 256, 0, stream>>>(
        user_table, ent_table, rel_table, w_ih0, w_hh0, b_ih0, b_hh0,
        users, items, lp0, final_buf);
    agg_kernel<<<(BN * D) / 256, 256, 0, stream>>>(
        nullptr, ent_table, items, final_buf, agg_w, agg_b, emb0);
    hop_kernel<5, 3><<<hop_blocks, 256, 0, stream>>>(
        user_table, ent_table, rel_table, w_ih1, w_hh1, b_ih1, b_hh1,
        users, items, lp1, final_buf);
    agg_kernel<<<(BN * D) / 256, 256, 0, stream>>>(
        emb0, ent_table, items, final_buf, agg_w, agg_b, emb1);
    score_kernel<<<BN / 256, 256, 0, stream>>>(
        user_table, emb1, users, items, ratings, out, partials);
    loss_kernel<<<1, 64, 0, stream>>>(partials, out);
}

// Round 2
// 636.899 us; speedup vs baseline: 1.0040x; 1.0040x over previous
//
#include <hip/hip_runtime.h>
#include <math.h>

#define D  32
#define BN 16384
#define PP 16

__device__ __forceinline__ float sigf(float x) { return 1.0f / (1.0f + __expf(-x)); }
__device__ __forceinline__ float tanh_fast(float x) {
    float e = __expf(2.0f * x);
    return 1.0f - 2.0f / (e + 1.0f);
}
__device__ __forceinline__ float logsigf(float x) {
    float ax = fabsf(x);
    float l = log1pf(__expf(-ax));
    return (x >= 0.0f) ? -l : x - l;
}

// Block = 256 threads = 4 waves; 64 pairs per block (lane = pair), wave w owns
// hidden units [8w, 8w+8). x/hprev pinned in VGPRs (asm opacity), h/c state in
// LDS laid out [unit][pair] (consecutive lanes -> conflict-free, no padding).
// Weight rows are wave-uniform (readfirstlane) -> scalar or broadcast loads.
template<int L, int T>
__global__ __launch_bounds__(256, 4)
void hop_kernel(const float* __restrict__ user_table,
                const float* __restrict__ ent_table,
                const float* __restrict__ rel_table,
                const float* __restrict__ w_ih,   // (128,64)
                const float* __restrict__ w_hh,   // (128,32)
                const float* __restrict__ b_ih,   // (128)
                const float* __restrict__ b_hh,   // (128)
                const int*   __restrict__ users,
                const int*   __restrict__ items,
                const int*   __restrict__ lp,     // (NE,P,L)
                float* __restrict__ final_out)    // (B,32)
{
    __shared__ float h_sh[32][64];   // h_sh[unit][pair]
    __shared__ float c_sh[32][64];   // c_sh[unit][pair]

    const int tid   = threadIdx.x;
    const int lane  = tid & 63;
    const int wave8 = __builtin_amdgcn_readfirstlane((tid >> 6) * 8);

    const int pairIdx = blockIdx.x * 64 + lane;
    const int b = pairIdx >> 4;
    const int item = items[b];
    const int user = users[b];
    const int* __restrict__ il = lp + ((size_t)item * PP + (pairIdx & 15)) * L;

    float x[64];

    // ---------------- step 0: x = [u, seed]; h=0 (skip w_hh), c=0 (skip f) ---
    {
        const int seed = il[0];
        const float4* s0 = reinterpret_cast<const float4*>(user_table + (size_t)user * D);
        const float4* s1 = reinterpret_cast<const float4*>(ent_table + (size_t)seed * D);
        #pragma unroll
        for (int q = 0; q < 8; ++q) {
            float4 v = s0[q];
            x[4*q+0] = v.x; x[4*q+1] = v.y; x[4*q+2] = v.z; x[4*q+3] = v.w;
        }
        #pragma unroll
        for (int q = 0; q < 8; ++q) {
            float4 v = s1[q];
            x[32+4*q+0] = v.x; x[32+4*q+1] = v.y; x[32+4*q+2] = v.z; x[32+4*q+3] = v.w;
        }
    }
    #pragma unroll
    for (int k = 0; k < 64; ++k) asm volatile("" : "+v"(x[k]));   // pin in VGPRs

    #pragma unroll 1
    for (int u = 0; u < 8; ++u) {
        const int j = __builtin_amdgcn_readfirstlane(wave8 + u);
        const float4* __restrict__ wi0 = reinterpret_cast<const float4*>(w_ih + (size_t)(j     ) * 64);
        const float4* __restrict__ wi2 = reinterpret_cast<const float4*>(w_ih + (size_t)(j + 64) * 64);
        const float4* __restrict__ wi3 = reinterpret_cast<const float4*>(w_ih + (size_t)(j + 96) * 64);
        float gi = b_ih[j     ] + b_hh[j     ];
        float gg = b_ih[j + 64] + b_hh[j + 64];
        float go = b_ih[j + 96] + b_hh[j + 96];
        #pragma unroll
        for (int q = 0; q < 16; ++q) {
            float4 a0 = wi0[q], a2 = wi2[q], a3 = wi3[q];
            gi = fmaf(a0.x, x[4*q+0], gi); gi = fmaf(a0.y, x[4*q+1], gi);
            gi = fmaf(a0.z, x[4*q+2], gi); gi = fmaf(a0.w, x[4*q+3], gi);
            gg = fmaf(a2.x, x[4*q+0], gg); gg = fmaf(a2.y, x[4*q+1], gg);
            gg = fmaf(a2.z, x[4*q+2], gg); gg = fmaf(a2.w, x[4*q+3], gg);
            go = fmaf(a3.x, x[4*q+0], go); go = fmaf(a3.y, x[4*q+1], go);
            go = fmaf(a3.z, x[4*q+2], go); go = fmaf(a3.w, x[4*q+3], go);
        }
        float cc = sigf(gi) * tanh_fast(gg);
        c_sh[j][lane] = cc;
        h_sh[j][lane] = sigf(go) * tanh_fast(cc);
    }

    // ---------------- steps 1..T-1: x = [rel, tail] --------------------------
    #pragma unroll 1
    for (int t = 1; t < T; ++t) {
        __syncthreads();                    // h writes of prev step visible
        float hprev[32];
        #pragma unroll
        for (int k = 0; k < 32; ++k) hprev[k] = h_sh[k][lane];
        #pragma unroll
        for (int k = 0; k < 32; ++k) asm volatile("" : "+v"(hprev[k]));
        __syncthreads();                    // everyone copied before overwrite

        const int ridx = il[2*t - 1];
        const int tidx = il[2*t];
        const float4* s0 = reinterpret_cast<const float4*>(rel_table + (size_t)ridx * D);
        const float4* s1 = reinterpret_cast<const float4*>(ent_table + (size_t)tidx * D);
        #pragma unroll
        for (int q = 0; q < 8; ++q) {
            float4 v = s0[q];
            x[4*q+0] = v.x; x[4*q+1] = v.y; x[4*q+2] = v.z; x[4*q+3] = v.w;
        }
        #pragma unroll
        for (int q = 0; q < 8; ++q) {
            float4 v = s1[q];
            x[32+4*q+0] = v.x; x[32+4*q+1] = v.y; x[32+4*q+2] = v.z; x[32+4*q+3] = v.w;
        }
        #pragma unroll
        for (int k = 0; k < 64; ++k) asm volatile("" : "+v"(x[k]));

        #pragma unroll 1
        for (int u = 0; u < 8; ++u) {
            const int j = __builtin_amdgcn_readfirstlane(wave8 + u);
            const float4* __restrict__ wi0 = reinterpret_cast<const float4*>(w_ih + (size_t)(j     ) * 64);
            const float4* __restrict__ wi1 = reinterpret_cast<const float4*>(w_ih + (size_t)(j + 32) * 64);
            const float4* __restrict__ wi2 = reinterpret_cast<const float4*>(w_ih + (size_t)(j + 64) * 64);
            const float4* __restrict__ wi3 = reinterpret_cast<const float4*>(w_ih + (size_t)(j + 96) * 64);
            float gi = b_ih[j     ] + b_hh[j     ];
            float gf = b_ih[j + 32] + b_hh[j + 32];
            float gg = b_ih[j + 64] + b_hh[j + 64];
            float go = b_ih[j + 96] + b_hh[j + 96];
            #pragma unroll
            for (int q = 0; q < 16; ++q) {
                float4 a0 = wi0[q], a1 = wi1[q], a2 = wi2[q], a3 = wi3[q];
                gi = fmaf(a0.x, x[4*q+0], gi); gi = fmaf(a0.y, x[4*q+1], gi);
                gi = fmaf(a0.z, x[4*q+2], gi); gi = fmaf(a0.w, x[4*q+3], gi);
                gf = fmaf(a1.x, x[4*q+0], gf); gf = fmaf(a1.y, x[4*q+1], gf);
                gf = fmaf(a1.z, x[4*q+2], gf); gf = fmaf(a1.w, x[4*q+3], gf);
                gg = fmaf(a2.x, x[4*q+0], gg); gg = fmaf(a2.y, x[4*q+1], gg);
                gg = fmaf(a2.z, x[4*q+2], gg); gg = fmaf(a2.w, x[4*q+3], gg);
                go = fmaf(a3.x, x[4*q+0], go); go = fmaf(a3.y, x[4*q+1], go);
                go = fmaf(a3.z, x[4*q+2], go); go = fmaf(a3.w, x[4*q+3], go);
            }
            const float4* __restrict__ wh0 = reinterpret_cast<const float4*>(w_hh + (size_t)(j     ) * 32);
            const float4* __restrict__ wh1 = reinterpret_cast<const float4*>(w_hh + (size_t)(j + 32) * 32);
            const float4* __restrict__ wh2 = reinterpret_cast<const float4*>(w_hh + (size_t)(j + 64) * 32);
            const float4* __restrict__ wh3 = reinterpret_cast<const float4*>(w_hh + (size_t)(j + 96) * 32);
            #pragma unroll
            for (int q = 0; q < 8; ++q) {
                float4 a0 = wh0[q], a1 = wh1[q], a2 = wh2[q], a3 = wh3[q];
                gi = fmaf(a0.x, hprev[4*q+0], gi); gi = fmaf(a0.y, hprev[4*q+1], gi);
                gi = fmaf(a0.z, hprev[4*q+2], gi); gi = fmaf(a0.w, hprev[4*q+3], gi);
                gf = fmaf(a1.x, hprev[4*q+0], gf); gf = fmaf(a1.y, hprev[4*q+1], gf);
                gf = fmaf(a1.z, hprev[4*q+2], gf); gf = fmaf(a1.w, hprev[4*q+3], gf);
                gg = fmaf(a2.x, hprev[4*q+0], gg); gg = fmaf(a2.y, hprev[4*q+1], gg);
                gg = fmaf(a2.z, hprev[4*q+2], gg); gg = fmaf(a2.w, hprev[4*q+3], gg);
                go = fmaf(a3.x, hprev[4*q+0], go); go = fmaf(a3.y, hprev[4*q+1], go);
                go = fmaf(a3.z, hprev[4*q+2], go); go = fmaf(a3.w, hprev[4*q+3], go);
            }
            float cold = c_sh[j][lane];
            float cc = sigf(gf) * cold + sigf(gi) * tanh_fast(gg);
            c_sh[j][lane] = cc;
            h_sh[j][lane] = sigf(go) * tanh_fast(cc);
        }
    }

    // ---------------- epilogue: sum over p (16-lane groups) ------------------
    __syncthreads();
    #pragma unroll
    for (int u = 0; u < 8; ++u) {
        const int j = wave8 + u;
        float v = h_sh[j][lane];
        v += __shfl_xor(v, 1);
        v += __shfl_xor(v, 2);
        v += __shfl_xor(v, 4);
        v += __shfl_xor(v, 8);
        if ((lane & 15) == 0)
            final_out[(size_t)b * D + j] = v;
    }
}

// out_emb[b][j] = agg_b[j] + sum_k (src[b][k] + final[b][k]) * agg_w[j][k]
__global__ __launch_bounds__(256)
void agg_kernel(const float* __restrict__ src_emb,   // may be null -> gather ent[items]
                const float* __restrict__ ent_table,
                const int*   __restrict__ items,
                const float* __restrict__ final_in,
                const float* __restrict__ agg_w,
                const float* __restrict__ agg_b,
                float* __restrict__ out_emb)
{
    const int t = blockIdx.x * 256 + threadIdx.x;   // B*32 threads
    const int b = t >> 5;
    const int j = t & 31;
    const float* __restrict__ src =
        src_emb ? (src_emb + (size_t)b * D) : (ent_table + (size_t)items[b] * D);
    const float* __restrict__ fin = final_in + (size_t)b * D;
    const float* __restrict__ w   = agg_w + (size_t)j * D;
    float acc = agg_b[j];
    #pragma unroll
    for (int k = 0; k < D; ++k) acc = fmaf(src[k] + fin[k], w[k], acc);
    out_emb[t] = acc;
}

__global__ __launch_bounds__(256)
void score_kernel(const float* __restrict__ user_table,
                  const float* __restrict__ emb,
                  const int*   __restrict__ users,
                  const int*   __restrict__ items,
                  const int*   __restrict__ ratings,
                  float* __restrict__ out,
                  float* __restrict__ partials)
{
    __shared__ float red[4];
    const int t = threadIdx.x;
    const int b = blockIdx.x * 256 + t;
    const float* __restrict__ u = user_table + (size_t)users[b] * D;
    const float* __restrict__ e = emb + (size_t)b * D;
    float s = 0.0f;
    #pragma unroll
    for (int k = 0; k < D; ++k) s = fmaf(u[k], e[k], s);
    out[1 + b]      = sigf(s);
    out[1 + BN + b] = (float)items[b];
    float r = (float)ratings[b];
    float term = r * logsigf(s) + (1.0f - r) * logsigf(-s);
    #pragma unroll
    for (int m = 1; m < 64; m <<= 1) term += __shfl_xor(term, m);
    if ((t & 63) == 0) red[t >> 6] = term;
    __syncthreads();
    if (t == 0) partials[blockIdx.x] = red[0] + red[1] + red[2] + red[3];
}

__global__ void loss_kernel(const float* __restrict__ partials, float* __restrict__ out)
{
    const int t = threadIdx.x;   // 64 threads
    float v = partials[t];
    #pragma unroll
    for (int m = 1; m < 64; m <<= 1) v += __shfl_xor(v, m);
    if (t == 0) out[0] = -v / (float)BN;
}

extern "C" void kernel_launch(void* const* d_in, const int* in_sizes, int n_in,
                              void* d_out, int out_size, void* d_ws, size_t ws_size,
                              hipStream_t stream)
{
    const float* user_table = (const float*)d_in[0];
    const float* ent_table  = (const float*)d_in[1];
    const float* rel_table  = (const float*)d_in[2];
    const float* w_ih0 = (const float*)d_in[3];
    const float* w_hh0 = (const float*)d_in[4];
    const float* b_ih0 = (const float*)d_in[5];
    const float* b_hh0 = (const float*)d_in[6];
    const float* w_ih1 = (const float*)d_in[7];
    const float* w_hh1 = (const float*)d_in[8];
    const float* b_ih1 = (const float*)d_in[9];
    const float* b_hh1 = (const float*)d_in[10];
    const float* agg_w = (const float*)d_in[11];
    const float* agg_b = (const float*)d_in[12];
    const int* users   = (const int*)d_in[13];
    const int* items   = (const int*)d_in[14];
    const int* ratings = (const int*)d_in[15];
    const int* lp0     = (const int*)d_in[16];
    const int* lp1     = (const int*)d_in[17];
    float* out = (float*)d_out;

    float* ws        = (float*)d_ws;
    float* final_buf = ws;                          // B*32
    float* emb0      = ws + (size_t)BN * D;         // B*32
    float* emb1      = ws + 2 * (size_t)BN * D;     // B*32
    float* partials  = ws + 3 * (size_t)BN * D;     // 64

    const int hop_blocks = (BN * PP) / 64;          // 4096
    hop_kernel<3, 2><<<hop_blocks, 256, 0, stream>>>(
        user_table, ent_table, rel_table, w_ih0, w_hh0, b_ih0, b_hh0,
        users, items, lp0, final_buf);
    agg_kernel<<<(BN * D) / 256, 256, 0, stream>>>(
        nullptr, ent_table, items, final_buf, agg_w, agg_b, emb0);
    hop_kernel<5, 3><<<hop_blocks, 256, 0, stream>>>(
        user_table, ent_table, rel_table, w_ih1, w_hh1, b_ih1, b_hh1,
        users, items, lp1, final_buf);
    agg_kernel<<<(BN * D) / 256, 256, 0, stream>>>(
        emb0, ent_table, items, final_buf, agg_w, agg_b, emb1);
    score_kernel<<<BN / 256, 256, 0, stream>>>(
        user_table, emb1, users, items, ratings, out, partials);
    loss_kernel<<<1, 64, 0, stream>>>(partials, out);
}

// Round 4
// 249.328 us; speedup vs baseline: 2.5646x; 2.5545x over previous
//
#include <hip/hip_runtime.h>
#include <math.h>

#define D  32
#define BN 16384
#define PP 16

typedef __bf16 bf16x8 __attribute__((ext_vector_type(8)));
typedef float  floatx4 __attribute__((ext_vector_type(4)));

// Weights image layout (bytes), one per hop, built by prep_weights:
//   [0, 18432)      W_ih as bf16, 128 rows, row-stride 72 elems (k = 0..63 valid)
//   [18432, 28672)  W_hh as bf16, 128 rows, row-stride 40 elems (k = 0..31 valid)
//   [28672, 29184)  bias fp32[128] = b_ih + b_hh
#define IMG_BYTES   29184
#define WIH_OFF     0
#define WHH_OFF     18432
#define BIAS_OFF    28672
#define X_OFF       29184            // X tile: 64 rows stride 72 bf16 (9216 B)
#define H_OFF       38400            // H tile: 64 rows stride 40 bf16 (5120 B)
#define LDS_BYTES   43520

__device__ __forceinline__ float sigf(float x) {
    // 1/(1+exp(-x)) ; v_exp_f32 is 2^x so pre-scale by log2(e)
    float e = __builtin_amdgcn_exp2f(-x * 1.44269504088896341f);
    return __builtin_amdgcn_rcpf(1.0f + e);
}
__device__ __forceinline__ float tanh_fast(float x) {
    float e = __builtin_amdgcn_exp2f(x * 2.88539008177792681f);  // exp(2x)
    return 1.0f - 2.0f * __builtin_amdgcn_rcpf(e + 1.0f);
}
__device__ __forceinline__ float logsigf(float x) {
    float ax = fabsf(x);
    float l = log1pf(__expf(-ax));
    return (x >= 0.0f) ? -l : x - l;
}

__device__ __forceinline__ void stage16(const float* __restrict__ src, char* dst) {
    const float4* s = (const float4*)src;
    float4 a = s[0], b = s[1], c = s[2], d = s[3];
    bf16x8 lo = { (__bf16)a.x, (__bf16)a.y, (__bf16)a.z, (__bf16)a.w,
                  (__bf16)b.x, (__bf16)b.y, (__bf16)b.z, (__bf16)b.w };
    bf16x8 hi = { (__bf16)c.x, (__bf16)c.y, (__bf16)c.z, (__bf16)c.w,
                  (__bf16)d.x, (__bf16)d.y, (__bf16)d.z, (__bf16)d.w };
    *(bf16x8*)dst        = lo;
    *(bf16x8*)(dst + 16) = hi;
}

// Build bf16 weight image for one hop.
__global__ __launch_bounds__(256)
void prep_weights(const float* __restrict__ w_ih, const float* __restrict__ w_hh,
                  const float* __restrict__ b_ih, const float* __restrict__ b_hh,
                  float* __restrict__ img_f)
{
    char* base = (char*)img_f;
    const int t0 = blockIdx.x * 256 + threadIdx.x;
    for (int idx = t0; idx < 8192; idx += 2048) {
        int n = idx >> 6, k = idx & 63;
        ((__bf16*)(base + WIH_OFF))[n * 72 + k] = (__bf16)w_ih[idx];
    }
    for (int idx = t0; idx < 4096; idx += 2048) {
        int n = idx >> 5, k = idx & 31;
        ((__bf16*)(base + WHH_OFF))[n * 40 + k] = (__bf16)w_hh[idx];
    }
    if (t0 < 128)
        ((float*)(base + BIAS_OFF))[t0] = b_ih[t0] + b_hh[t0];
}

// Block = 256 thr = 4 waves. Wave w owns pairs [blockIdx*64 + 16w, +16) = all 16
// p's of batch b = blockIdx*4 + w. MFMA 16x16x32 bf16: gates G(16 pairs x 128)
// = X(16x64)@Wih^T + H(16x32)@Whh^T + bias. All X/H staging and A-frag reads are
// wave-private -> no __syncthreads in the step loop.
template<int L, int T>
__global__ __launch_bounds__(256, 2)
void hop_mfma(const float* __restrict__ user_table,
              const float* __restrict__ ent_table,
              const float* __restrict__ rel_table,
              const float* __restrict__ img,      // weights image (bf16/f32)
              const int*   __restrict__ users,
              const int*   __restrict__ items,
              const int*   __restrict__ lp,       // (NE,P,L)
              float* __restrict__ final_out)      // (B,32)
{
    __shared__ __align__(16) char lds[LDS_BYTES];

    const int tid  = threadIdx.x;
    const int lane = tid & 63;
    const int wave = tid >> 6;

    // ---- load weight image into LDS (block-wide), the only barrier ----------
    {
        const float4* g = (const float4*)img;
        float4* l = (float4*)lds;
        #pragma unroll
        for (int i = 0; i < 8; ++i) {
            int idx = i * 256 + tid;                 // IMG_BYTES/16 = 1824
            if (idx < IMG_BYTES / 16) l[idx] = g[idx];
        }
    }
    __syncthreads();

    char* Wih  = lds + WIH_OFF;
    char* Whh  = lds + WHH_OFF;
    const float* bias = (const float*)(lds + BIAS_OFF);
    char* Xl   = lds + X_OFF;
    char* Hl   = lds + H_OFF;

    // ---- staging role: thread stages 16 feats of row srow -------------------
    const int srow  = tid >> 2;          // 0..63  (wave-private: rows 16w..16w+15)
    const int squad = tid & 3;
    const int spair = blockIdx.x * 64 + srow;
    const int sb    = spair >> 4;
    const int sp    = spair & 15;
    const int sitem = items[sb];
    const int suser = users[sb];
    const int* __restrict__ sil = lp + ((size_t)sitem * PP + sp) * L;
    char* sdst = Xl + srow * 144 + squad * 32;

    // ---- MFMA role ----------------------------------------------------------
    const int wrow = wave * 16;
    const int am   = wrow + (lane & 15);           // A row (pair)
    const int ak   = (lane >> 4) * 8;              // A/B k-offset
    const int bnl  = lane & 15;                    // B col within tile

    float cst[8]  = {0,0,0,0,0,0,0,0};
    float hout[8];
    floatx4 acc[8];
    #pragma unroll
    for (int nt = 0; nt < 8; ++nt) {
        float bv = bias[nt * 16 + bnl];
        floatx4 v = { bv, bv, bv, bv };
        acc[nt] = v;
    }

    #pragma unroll
    for (int t = 0; t < T; ++t) {
        // stage X_t (wave-private rows)
        {
            const float* src;
            if (t == 0) {
                src = (squad < 2) ? user_table + (size_t)suser * D + squad * 16
                                  : ent_table + (size_t)sil[0] * D + (squad - 2) * 16;
            } else {
                src = (squad < 2) ? rel_table + (size_t)sil[2 * t - 1] * D + squad * 16
                                  : ent_table + (size_t)sil[2 * t]     * D + (squad - 2) * 16;
            }
            stage16(src, sdst);
        }

        // A fragments
        bf16x8 ax0 = *(const bf16x8*)(Xl + am * 144 + ak * 2);
        bf16x8 ax1 = *(const bf16x8*)(Xl + am * 144 + 64 + ak * 2);
        bf16x8 ah  = {};
        if (t > 0) ah = *(const bf16x8*)(Hl + am * 80 + ak * 2);

        #pragma unroll
        for (int nt = 0; nt < 8; ++nt) {
            const int bn = nt * 16 + bnl;
            bf16x8 b0 = *(const bf16x8*)(Wih + bn * 144 + ak * 2);
            bf16x8 b1 = *(const bf16x8*)(Wih + bn * 144 + 64 + ak * 2);
            floatx4 a = acc[nt];
            a = __builtin_amdgcn_mfma_f32_16x16x32_bf16(ax0, b0, a, 0, 0, 0);
            a = __builtin_amdgcn_mfma_f32_16x16x32_bf16(ax1, b1, a, 0, 0, 0);
            if (t > 0) {
                bf16x8 bh = *(const bf16x8*)(Whh + bn * 80 + ak * 2);
                a = __builtin_amdgcn_mfma_f32_16x16x32_bf16(ah, bh, a, 0, 0, 0);
            }
            acc[nt] = a;
        }

        // gate nonlinearities in C-layout: col=lane&15 (+16*nt), row=(lane>>4)*4+reg
        #pragma unroll
        for (int ng = 0; ng < 2; ++ng) {
            floatx4 gi = acc[ng], gf = acc[ng + 2], gg = acc[ng + 4], go = acc[ng + 6];
            #pragma unroll
            for (int r = 0; r < 4; ++r) {
                float c = cst[ng * 4 + r];
                c = sigf(gf[r]) * c + sigf(gi[r]) * tanh_fast(gg[r]);
                cst[ng * 4 + r] = c;
                float h = sigf(go[r]) * tanh_fast(c);
                hout[ng * 4 + r] = h;
                if (t < T - 1) {
                    int pr = wrow + (lane >> 4) * 4 + r;
                    int un = ng * 16 + bnl;
                    *(__bf16*)(Hl + pr * 80 + un * 2) = (__bf16)h;
                }
            }
        }

        if (t < T - 1) {
            #pragma unroll
            for (int nt = 0; nt < 8; ++nt) {
                float bv = bias[nt * 16 + bnl];
                floatx4 v = { bv, bv, bv, bv };
                acc[nt] = v;
            }
        }
    }

    // ---- reduce over the wave's 16 pairs (= all p of batch fb) --------------
    const int fb = blockIdx.x * 4 + wave;
    #pragma unroll
    for (int ng = 0; ng < 2; ++ng) {
        float v = hout[ng * 4 + 0] + hout[ng * 4 + 1] + hout[ng * 4 + 2] + hout[ng * 4 + 3];
        v += __shfl_xor(v, 16);
        v += __shfl_xor(v, 32);
        if (lane < 16)
            final_out[(size_t)fb * D + ng * 16 + lane] = v;
    }
}

// out_emb[b][j] = agg_b[j] + sum_k (src[b][k] + final[b][k]) * agg_w[j][k]
__global__ __launch_bounds__(256)
void agg_kernel(const float* __restrict__ src_emb,   // null -> gather ent[items]
                const float* __restrict__ ent_table,
                const int*   __restrict__ items,
                const float* __restrict__ final_in,
                const float* __restrict__ agg_w,
                const float* __restrict__ agg_b,
                float* __restrict__ out_emb)
{
    const int t = blockIdx.x * 256 + threadIdx.x;   // B*32 threads
    const int b = t >> 5;
    const int j = t & 31;
    const float* __restrict__ src =
        src_emb ? (src_emb + (size_t)b * D) : (ent_table + (size_t)items[b] * D);
    const float* __restrict__ fin = final_in + (size_t)b * D;
    const float* __restrict__ w   = agg_w + (size_t)j * D;
    float acc = agg_b[j];
    #pragma unroll
    for (int k = 0; k < D; ++k) acc = fmaf(src[k] + fin[k], w[k], acc);
    out_emb[t] = acc;
}

__global__ __launch_bounds__(256)
void score_kernel(const float* __restrict__ user_table,
                  const float* __restrict__ emb,
                  const int*   __restrict__ users,
                  const int*   __restrict__ items,
                  const int*   __restrict__ ratings,
                  float* __restrict__ out,
                  float* __restrict__ partials)
{
    __shared__ float red[4];
    const int t = threadIdx.x;
    const int b = blockIdx.x * 256 + t;
    const float* __restrict__ u = user_table + (size_t)users[b] * D;
    const float* __restrict__ e = emb + (size_t)b * D;
    float s = 0.0f;
    #pragma unroll
    for (int k = 0; k < D; ++k) s = fmaf(u[k], e[k], s);
    out[1 + b]      = sigf(s);
    out[1 + BN + b] = (float)items[b];
    float r = (float)ratings[b];
    float term = r * logsigf(s) + (1.0f - r) * logsigf(-s);
    #pragma unroll
    for (int m = 1; m < 64; m <<= 1) term += __shfl_xor(term, m);
    if ((t & 63) == 0) red[t >> 6] = term;
    __syncthreads();
    if (t == 0) partials[blockIdx.x] = red[0] + red[1] + red[2] + red[3];
}

__global__ void loss_kernel(const float* __restrict__ partials, float* __restrict__ out)
{
    const int t = threadIdx.x;   // 64 threads
    float v = partials[t];
    #pragma unroll
    for (int m = 1; m < 64; m <<= 1) v += __shfl_xor(v, m);
    if (t == 0) out[0] = -v / (float)BN;
}

extern "C" void kernel_launch(void* const* d_in, const int* in_sizes, int n_in,
                              void* d_out, int out_size, void* d_ws, size_t ws_size,
                              hipStream_t stream)
{
    const float* user_table = (const float*)d_in[0];
    const float* ent_table  = (const float*)d_in[1];
    const float* rel_table  = (const float*)d_in[2];
    const float* w_ih0 = (const float*)d_in[3];
    const float* w_hh0 = (const float*)d_in[4];
    const float* b_ih0 = (const float*)d_in[5];
    const float* b_hh0 = (const float*)d_in[6];
    const float* w_ih1 = (const float*)d_in[7];
    const float* w_hh1 = (const float*)d_in[8];
    const float* b_ih1 = (const float*)d_in[9];
    const float* b_hh1 = (const float*)d_in[10];
    const float* agg_w = (const float*)d_in[11];
    const float* agg_b = (const float*)d_in[12];
    const int* users   = (const int*)d_in[13];
    const int* items   = (const int*)d_in[14];
    const int* ratings = (const int*)d_in[15];
    const int* lp0     = (const int*)d_in[16];
    const int* lp1     = (const int*)d_in[17];
    float* out = (float*)d_out;

    float* ws        = (float*)d_ws;
    float* final_buf = ws;                          // B*32
    float* emb0      = ws + (size_t)BN * D;         // B*32
    float* emb1      = ws + 2 * (size_t)BN * D;     // B*32
    float* partials  = ws + 3 * (size_t)BN * D;     // 64
    float* img0      = ws + 3 * (size_t)BN * D + 64;            // 29184 B
    float* img1      = img0 + IMG_BYTES / 4;                    // 29184 B

    prep_weights<<<8, 256, 0, stream>>>(w_ih0, w_hh0, b_ih0, b_hh0, img0);
    prep_weights<<<8, 256, 0, stream>>>(w_ih1, w_hh1, b_ih1, b_hh1, img1);

    const int hop_blocks = (BN * PP) / 64;          // 4096
    hop_mfma<3, 2><<<hop_blocks, 256, 0, stream>>>(
        user_table, ent_table, rel_table, img0, users, items, lp0, final_buf);
    agg_kernel<<<(BN * D) / 256, 256, 0, stream>>>(
        nullptr, ent_table, items, final_buf, agg_w, agg_b, emb0);
    hop_mfma<5, 3><<<hop_blocks, 256, 0, stream>>>(
        user_table, ent_table, rel_table, img1, users, items, lp1, final_buf);
    agg_kernel<<<(BN * D) / 256, 256, 0, stream>>>(
        emb0, ent_table, items, final_buf, agg_w, agg_b, emb1);
    score_kernel<<<BN / 256, 256, 0, stream>>>(
        user_table, emb1, users, items, ratings, out, partials);
    loss_kernel<<<1, 64, 0, stream>>>(partials, out);
}